// Round 8
// baseline (432.864 us; speedup 1.0000x reference)
//
#include <hip/hip_runtime.h>
#include <hip/hip_bf16.h>
#include <stdint.h>

#define B_ 256
#define T_ 512
#define C_ 14
#define CO_ 32
#define H_ 128
#define G_ 512   // 4*H

__device__ __forceinline__ float sigm_fast(float x) {
  float e = __expf(-x);
  return __builtin_amdgcn_rcpf(1.f + e);
}
__device__ __forceinline__ float tanh_fast(float x) {
  float e = __expf(2.f * x);               // inf-safe: x>>0 -> 1, x<<0 -> -1
  return 1.f - 2.f * __builtin_amdgcn_rcpf(1.f + e);
}

// Fast path is provable: mem = o*tanh(syn) - reset*thr < 1 always (o<1,
// |tanh|<1). Spike needs mem - thr1 > 0, impossible when thr1 >= 1, so
// layer-1 spikes are identically zero for ANY x/weights. Each kernel
// evaluates thr1[0] >= 1 directly (no flag kernel / buffer).

// ---------------- Kernel 1: conv over time + Leaky spike (fallback) --------
__global__ __launch_bounds__(256) void k_conv_spike(
    const float* __restrict__ thr1_p, const float* __restrict__ x,
    const float* __restrict__ cw, const float* __restrict__ cb,
    unsigned int* __restrict__ cur1) {
  if (thr1_p[0] >= 1.0f) return;
  __shared__ float w_s[CO_ * C_ * 3];
  __shared__ float b_s[CO_];
  for (int i = threadIdx.x; i < CO_ * C_ * 3; i += blockDim.x) w_s[i] = cw[i];
  if (threadIdx.x < CO_) b_s[threadIdx.x] = cb[threadIdx.x];
  __syncthreads();
  int idx = blockIdx.x * blockDim.x + threadIdx.x;  // b*T + t
  if (idx >= B_ * T_) return;
  int b = idx / T_, t = idx % T_;
  float xin[3][C_];
#pragma unroll
  for (int k = 0; k < 3; ++k) {
    int tt = t + k - 1;
    if (tt < 0 || tt >= T_) {
#pragma unroll
      for (int c = 0; c < C_; ++c) xin[k][c] = 0.f;
    } else {
      const float* p = x + ((size_t)b * T_ + tt) * C_;
#pragma unroll
      for (int c = 0; c < C_; ++c) xin[k][c] = p[c];
    }
  }
  unsigned int bits = 0u;
  for (int oc = 0; oc < CO_; ++oc) {
    float s = b_s[oc];
    const float* wr = &w_s[oc * C_ * 3];
#pragma unroll
    for (int ic = 0; ic < C_; ++ic)
#pragma unroll
      for (int k = 0; k < 3; ++k) s = fmaf(xin[k][ic], wr[ic * 3 + k], s);
    if (s - 1.0f > 0.f) bits |= (1u << oc);
  }
  cur1[idx] = bits;
}

// ---------------- Kernel 2: honest SLSTM layer 1 (fallback only) -----------
__global__ __launch_bounds__(512, 2) void k_slstm1(
    const unsigned int* __restrict__ cur1,
    const float* __restrict__ w_ih, const float* __restrict__ w_hh,
    const float* __restrict__ b_ih, const float* __restrict__ b_hh,
    const float* __restrict__ thr_p, unsigned long long* __restrict__ spk_bits,
    unsigned int* __restrict__ count) {
  if (thr_p[0] >= 1.0f) return;  // spikes provably zero; count stays 0
  const int g = threadIdx.x;
  const int t0 = blockIdx.x * 2;
  const float thr = thr_p[0];
  float wih[32], whh[H_];
#pragma unroll
  for (int k = 0; k < 32; ++k) wih[k] = w_ih[g * 32 + k];
#pragma unroll
  for (int k = 0; k < H_; ++k) whh[k] = w_hh[g * H_ + k];
  const float bias = b_ih[g] + b_hh[g];
  __shared__ float mem_s[2][H_];
  __shared__ float gate_s[2][G_];
  float syn = 0.f;
  int cnt = 0;
  if (g < 256) mem_s[g >> 7][g & 127] = 0.f;
  __syncthreads();
  for (int b = 0; b < B_; ++b) {
    unsigned int bits0 = cur1[b * T_ + t0];
    unsigned int bits1 = cur1[b * T_ + t0 + 1];
    float s0 = bias, s1 = bias;
#pragma unroll
    for (int k = 0; k < 32; ++k) {
      s0 += ((bits0 >> k) & 1u) ? wih[k] : 0.f;
      s1 += ((bits1 >> k) & 1u) ? wih[k] : 0.f;
    }
#pragma unroll
    for (int k = 0; k < H_; ++k) {
      s0 = fmaf(whh[k], mem_s[0][k], s0);
      s1 = fmaf(whh[k], mem_s[1][k], s1);
    }
    gate_s[0][g] = s0;
    gate_s[1][g] = s1;
    __syncthreads();
    if (g < 256) {
      const int r = g >> 7, h = g & 127;
      float gi = gate_s[r][h];
      float gf = gate_s[r][h + 128];
      float gg = gate_s[r][h + 256];
      float go = gate_s[r][h + 384];
      float ii = 1.f / (1.f + expf(-gi));
      float ff = 1.f / (1.f + expf(-gf));
      float gt = tanhf(gg);
      float oo = 1.f / (1.f + expf(-go));
      float memp = mem_s[r][h];
      float rst = (memp - thr > 0.f) ? thr : 0.f;
      syn = ff * syn + ii * gt;
      float mm = oo * tanhf(syn) - rst;
      mem_s[r][h] = mm;
      bool spk = (mm - thr) > 0.f;
      cnt += spk ? 1 : 0;
      unsigned long long m = __ballot(spk);
      if ((g & 63) == 0)
        spk_bits[((size_t)b * T_ + t0 + r) * 2 + ((h >> 6) & 1)] = m;
    }
    __syncthreads();
  }
  if (g < 256) atomicAdd(&count[g & 127], (unsigned int)cnt);
}

// ---------------- Kernel 3: BN params from spike counts (both paths) -------
__global__ void k_bnprep(const unsigned int* __restrict__ count,
                         const float* __restrict__ gamma,
                         const float* __restrict__ beta,
                         float* __restrict__ a, float* __restrict__ c) {
  int h = threadIdx.x;
  if (h >= H_) return;
  const float inv_n = 1.f / (float)(B_ * T_);
  float mu = (float)count[h] * inv_n;
  float var = mu * (1.f - mu);
  float ai = gamma[h] / sqrtf(var + 1e-5f);
  a[h] = ai;
  c[h] = beta[h] - mu * ai;
}

// ---------------- Kernel 4: fold BN into layer-2 weights (cg both paths) ---
__global__ void k_fold(const float* __restrict__ thr1_p,
                       const float* __restrict__ w_ih2,
                       const float* __restrict__ b_ih2,
                       const float* __restrict__ b_hh2,
                       const float* __restrict__ a, const float* __restrict__ c,
                       float* __restrict__ W2p, float* __restrict__ cg) {
  int gi = blockIdx.x * blockDim.x + threadIdx.x;  // 0..511
  if (gi >= G_) return;
  const int fast = thr1_p[0] >= 1.0f;
  float s = b_ih2[gi] + b_hh2[gi];
  for (int h = 0; h < H_; ++h) {
    float w = w_ih2[gi * H_ + h];
    if (!fast) W2p[h * G_ + gi] = w * a[h];  // fallback-only matrix
    s = fmaf(w, c[h], s);
  }
  cg[gi] = s;
}

// ---------------- Kernel 5: honest SLSTM layer 2 (fallback only) -----------
__global__ __launch_bounds__(512, 2) void k_slstm2(
    const float* __restrict__ thr1_p,
    const unsigned long long* __restrict__ spk_bits,
    const float* __restrict__ w_hh, const float* __restrict__ W2p,
    const float* __restrict__ cg, const float* __restrict__ thr_p,
    float* __restrict__ acc_out) {
  if (thr1_p[0] >= 1.0f) return;  // fast path handled by k_traj
  const int g = threadIdx.x;
  const int t0 = blockIdx.x * 2;
  const float thr = thr_p[0];
  float whh[H_];
#pragma unroll
  for (int k = 0; k < H_; ++k) whh[k] = w_hh[g * H_ + k];
  const float bias = cg[g];
  __shared__ float mem_s[2][H_];
  __shared__ float gate_s[2][G_];
  float syn = 0.f, accv = 0.f;
  if (g < 256) mem_s[g >> 7][g & 127] = 0.f;
  __syncthreads();
  for (int b = 0; b < B_; ++b) {
    unsigned long long m00 = spk_bits[((size_t)b * T_ + t0) * 2 + 0];
    unsigned long long m01 = spk_bits[((size_t)b * T_ + t0) * 2 + 1];
    unsigned long long m10 = spk_bits[((size_t)b * T_ + t0 + 1) * 2 + 0];
    unsigned long long m11 = spk_bits[((size_t)b * T_ + t0 + 1) * 2 + 1];
    float s0 = bias, s1 = bias;
    while (m00) { int h = __ffsll(m00) - 1; m00 &= m00 - 1; s0 += W2p[h * G_ + g]; }
    while (m01) { int h = __ffsll(m01) - 1; m01 &= m01 - 1; s0 += W2p[(h + 64) * G_ + g]; }
    while (m10) { int h = __ffsll(m10) - 1; m10 &= m10 - 1; s1 += W2p[h * G_ + g]; }
    while (m11) { int h = __ffsll(m11) - 1; m11 &= m11 - 1; s1 += W2p[(h + 64) * G_ + g]; }
#pragma unroll
    for (int k = 0; k < H_; ++k) {
      s0 = fmaf(whh[k], mem_s[0][k], s0);
      s1 = fmaf(whh[k], mem_s[1][k], s1);
    }
    gate_s[0][g] = s0;
    gate_s[1][g] = s1;
    __syncthreads();
    if (g < 256) {
      const int r = g >> 7, h = g & 127;
      float gi = gate_s[r][h];
      float gf = gate_s[r][h + 128];
      float gg = gate_s[r][h + 256];
      float go = gate_s[r][h + 384];
      float ii = 1.f / (1.f + expf(-gi));
      float ff = 1.f / (1.f + expf(-gf));
      float gt = tanhf(gg);
      float oo = 1.f / (1.f + expf(-go));
      float memp = mem_s[r][h];
      float rst = (memp - thr > 0.f) ? thr : 0.f;
      syn = ff * syn + ii * gt;
      float mm = oo * tanhf(syn) - rst;
      mem_s[r][h] = mm;
      accv += mm;
    }
    __syncthreads();
  }
  if (g < 256) acc_out[(size_t)(t0 + (g >> 7)) * H_ + (g & 127)] = accv;
}

// ---------------- Kernel 5b: FAST layer 2 — single shared trajectory -------
// thr1>=1 -> layer-2 input = beta every row/step -> ONE 256-step trajectory.
// 256 threads (4 waves, 1/SIMD, waves_per_eu(1,1) -> 512-VGPR budget).
// Thread t: h = t>>1, q = t&1 owns TWO full gates:
//   rowA = h + q*128        (i-gate if q==0, f-gate if q==1)
//   rowB = h + 256 + q*128  (g-gate if q==0, o-gate if q==1)
// 256 weights live in 64 named float4 (pinned "v"). Per step: 128 readlane
// broadcasts feed 2 FMAs each; activations finish IN-THREAD (no gate LDS);
// pair exchange via one shfl_xor; ONE barrier; mem double-buffered in LDS.
#define PIN4(v) asm volatile("" : "+v"(v.x), "+v"(v.y), "+v"(v.z), "+v"(v.w))
#define PIN16(P) PIN4(P##0); PIN4(P##1); PIN4(P##2); PIN4(P##3);

#define LD16(P, p, o)                              \
  float4 P##0 = *(const float4*)((p) + (o));       \
  float4 P##1 = *(const float4*)((p) + (o) + 4);   \
  float4 P##2 = *(const float4*)((p) + (o) + 8);   \
  float4 P##3 = *(const float4*)((p) + (o) + 12);

#define RLF(v, k) __uint_as_float(__builtin_amdgcn_readlane((v), (k)))

// NOTE: (A##0).x — parens required; "A##0.x" lexes "0.x" as one pp-number.
#define STEP16(A, B, vmx, base) {                                              \
    float mk;                                                                  \
    mk = RLF(vmx, (base) + 0);                                                 \
    a0 = fmaf((A##0).x, mk, a0); b0 = fmaf((B##0).x, mk, b0);                  \
    mk = RLF(vmx, (base) + 1);                                                 \
    a1 = fmaf((A##0).y, mk, a1); b1 = fmaf((B##0).y, mk, b1);                  \
    mk = RLF(vmx, (base) + 2);                                                 \
    a2 = fmaf((A##0).z, mk, a2); b2 = fmaf((B##0).z, mk, b2);                  \
    mk = RLF(vmx, (base) + 3);                                                 \
    a3 = fmaf((A##0).w, mk, a3); b3 = fmaf((B##0).w, mk, b3);                  \
    mk = RLF(vmx, (base) + 4);                                                 \
    a0 = fmaf((A##1).x, mk, a0); b0 = fmaf((B##1).x, mk, b0);                  \
    mk = RLF(vmx, (base) + 5);                                                 \
    a1 = fmaf((A##1).y, mk, a1); b1 = fmaf((B##1).y, mk, b1);                  \
    mk = RLF(vmx, (base) + 6);                                                 \
    a2 = fmaf((A##1).z, mk, a2); b2 = fmaf((B##1).z, mk, b2);                  \
    mk = RLF(vmx, (base) + 7);                                                 \
    a3 = fmaf((A##1).w, mk, a3); b3 = fmaf((B##1).w, mk, b3);                  \
    mk = RLF(vmx, (base) + 8);                                                 \
    a0 = fmaf((A##2).x, mk, a0); b0 = fmaf((B##2).x, mk, b0);                  \
    mk = RLF(vmx, (base) + 9);                                                 \
    a1 = fmaf((A##2).y, mk, a1); b1 = fmaf((B##2).y, mk, b1);                  \
    mk = RLF(vmx, (base) + 10);                                                \
    a2 = fmaf((A##2).z, mk, a2); b2 = fmaf((B##2).z, mk, b2);                  \
    mk = RLF(vmx, (base) + 11);                                                \
    a3 = fmaf((A##2).w, mk, a3); b3 = fmaf((B##2).w, mk, b3);                  \
    mk = RLF(vmx, (base) + 12);                                                \
    a0 = fmaf((A##3).x, mk, a0); b0 = fmaf((B##3).x, mk, b0);                  \
    mk = RLF(vmx, (base) + 13);                                                \
    a1 = fmaf((A##3).y, mk, a1); b1 = fmaf((B##3).y, mk, b1);                  \
    mk = RLF(vmx, (base) + 14);                                                \
    a2 = fmaf((A##3).z, mk, a2); b2 = fmaf((B##3).z, mk, b2);                  \
    mk = RLF(vmx, (base) + 15);                                                \
    a3 = fmaf((A##3).w, mk, a3); b3 = fmaf((B##3).w, mk, b3);                  \
  }

__global__ __launch_bounds__(256)
__attribute__((amdgpu_waves_per_eu(1, 1))) void k_traj(
    const float* __restrict__ thr1_p, const float* __restrict__ w_hh,
    const float* __restrict__ cg, const float* __restrict__ thr_p,
    const float* __restrict__ fc_w, const float* __restrict__ fc_b,
    float* __restrict__ out) {
  if (thr1_p[0] < 1.0f) return;
  const int t = threadIdx.x;
  const int h = t >> 1;
  const int q = t & 1;
  const int lane = t & 63;
  const float thr = thr_p[0];

  const int rowA = h + (q << 7);
  const int rowB = h + 256 + (q << 7);
  const float* pA = w_hh + (size_t)rowA * H_;
  const float* pB = w_hh + (size_t)rowB * H_;
  LD16(A0, pA, 0)  LD16(A1, pA, 16) LD16(A2, pA, 32) LD16(A3, pA, 48)
  LD16(A4, pA, 64) LD16(A5, pA, 80) LD16(A6, pA, 96) LD16(A7, pA, 112)
  LD16(Bb0, pB, 0)  LD16(Bb1, pB, 16) LD16(Bb2, pB, 32) LD16(Bb3, pB, 48)
  LD16(Bb4, pB, 64) LD16(Bb5, pB, 80) LD16(Bb6, pB, 96) LD16(Bb7, pB, 112)
  float biasA = cg[rowA];
  float biasB = cg[rowB];

  __shared__ float mbuf[2][H_];
  __shared__ float red_s[H_ + 8];
  float syn = 0.f, memp = 0.f, accm = 0.f;
  int vm0 = 0, vm1 = 0;  // bits of mem[lane], mem[64+lane]; mem_0 = 0

  for (int b = 0; b < B_; ++b) {
    PIN16(A0) PIN16(A1) PIN16(A2) PIN16(A3)
    PIN16(A4) PIN16(A5) PIN16(A6) PIN16(A7)
    PIN16(Bb0) PIN16(Bb1) PIN16(Bb2) PIN16(Bb3)
    PIN16(Bb4) PIN16(Bb5) PIN16(Bb6) PIN16(Bb7)
    asm volatile("" : "+v"(biasA), "+v"(biasB));
    // phase 1: two full 128-dots per thread, readlane broadcast operands
    float a0 = biasA, a1 = 0.f, a2 = 0.f, a3 = 0.f;
    float b0 = biasB, b1 = 0.f, b2 = 0.f, b3 = 0.f;
    STEP16(A0, Bb0, vm0, 0)  STEP16(A1, Bb1, vm0, 16)
    STEP16(A2, Bb2, vm0, 32) STEP16(A3, Bb3, vm0, 48)
    STEP16(A4, Bb4, vm1, 0)  STEP16(A5, Bb5, vm1, 16)
    STEP16(A6, Bb6, vm1, 32) STEP16(A7, Bb7, vm1, 48)
    float s0 = (a0 + a1) + (a2 + a3);   // preact rowA (i or f)
    float s1 = (b0 + b1) + (b2 + b3);   // preact rowB (g or o)
    // phase 2: in-thread activations; pair exchange with partner t^1
    float act0 = sigm_fast(s0);                      // i (q0) / f (q1)
    float act1 = q ? sigm_fast(s1) : tanh_fast(s1);  // g (q0) / o (q1)
    float px0 = __shfl_xor(act0, 1);                 // q0 gets f
    float px1 = __shfl_xor(act1, 1);                 // q0 gets o
    float* wb = mbuf[b & 1];
    if (q == 0) {
      float rst = (memp - thr > 0.f) ? thr : 0.f;    // honest reset (thr2)
      syn = px0 * syn + act0 * act1;
      float mm = px1 * tanh_fast(syn) - rst;
      memp = mm;
      accm += mm;
      wb[h] = mm;
    }
    __syncthreads();
    vm0 = __float_as_int(wb[lane]);
    vm1 = __float_as_int(wb[64 + lane]);
  }
  // mean over steps -> FC (8 outputs) -> broadcast to all 512 rows
  if (q == 0) red_s[h] = accm * (1.f / 256.f);
  __syncthreads();
  if (t < 8) {
    float s = fc_b[t];
    const float* fw = fc_w + t * H_;
    for (int k = 0; k < H_; ++k) s = fmaf(red_s[k], fw[k], s);
    red_s[H_ + t] = s;
  }
  __syncthreads();
  for (int idx = t; idx < T_ * 8; idx += 256) out[idx] = red_s[H_ + (idx & 7)];
}

// ---------------- Kernel 6: final mean + FC (fallback only) ----------------
__global__ void k_out(const float* __restrict__ thr1_p,
                      const float* __restrict__ accv,
                      const float* __restrict__ fc_w,
                      const float* __restrict__ fc_b, float* __restrict__ out) {
  if (thr1_p[0] >= 1.0f) return;
  int idx = blockIdx.x * blockDim.x + threadIdx.x;  // t*8+n
  if (idx >= T_ * 8) return;
  int t = idx >> 3, n = idx & 7;
  float s = fc_b[n];
  for (int h = 0; h < H_; ++h)
    s = fmaf(accv[t * H_ + h] * (1.f / 256.f), fc_w[n * H_ + h], s);
  out[idx] = s;
}

extern "C" void kernel_launch(void* const* d_in, const int* in_sizes, int n_in,
                              void* d_out, int out_size, void* d_ws, size_t ws_size,
                              hipStream_t stream) {
  const float* x       = (const float*)d_in[0];
  const float* conv_w  = (const float*)d_in[1];
  const float* conv_b  = (const float*)d_in[2];
  const float* w_ih1   = (const float*)d_in[3];
  const float* w_hh1   = (const float*)d_in[4];
  const float* b_ih1   = (const float*)d_in[5];
  const float* b_hh1   = (const float*)d_in[6];
  const float* thr1    = (const float*)d_in[7];
  const float* w_ih2   = (const float*)d_in[8];
  const float* w_hh2   = (const float*)d_in[9];
  const float* b_ih2   = (const float*)d_in[10];
  const float* b_hh2   = (const float*)d_in[11];
  const float* thr2    = (const float*)d_in[12];
  const float* bn_g    = (const float*)d_in[13];
  const float* bn_b    = (const float*)d_in[14];
  const float* fc_w    = (const float*)d_in[15];
  const float* fc_b    = (const float*)d_in[16];
  float* out = (float*)d_out;

  char* ws = (char*)d_ws;
  unsigned int* cur1       = (unsigned int*)(ws);                    // 512 KB
  unsigned long long* spk  = (unsigned long long*)(ws + (512 << 10));// 2 MB
  unsigned int* count      = (unsigned int*)(ws + (2560 << 10));     // 512 B
  float* a                 = (float*)(ws + (2561 << 10));            // 512 B
  float* c                 = (float*)(ws + (2562 << 10));            // 512 B
  float* cg                = (float*)(ws + (2563 << 10));            // 2 KB
  float* W2p               = (float*)(ws + (2566 << 10));            // 256 KB
  float* accv              = (float*)(ws + (2822 << 10));            // 256 KB

  hipMemsetAsync(count, 0, H_ * sizeof(unsigned int), stream);
  k_conv_spike<<<(B_ * T_ + 255) / 256, 256, 0, stream>>>(thr1, x, conv_w,
                                                          conv_b, cur1);
  k_slstm1<<<T_ / 2, 512, 0, stream>>>(cur1, w_ih1, w_hh1, b_ih1, b_hh1, thr1,
                                       spk, count);
  k_bnprep<<<1, 128, 0, stream>>>(count, bn_g, bn_b, a, c);
  k_fold<<<1, 512, 0, stream>>>(thr1, w_ih2, b_ih2, b_hh2, a, c, W2p, cg);
  k_slstm2<<<T_ / 2, 512, 0, stream>>>(thr1, spk, w_hh2, W2p, cg, thr2, accv);
  k_traj<<<1, 256, 0, stream>>>(thr1, w_hh2, cg, thr2, fc_w, fc_b, out);
  k_out<<<(T_ * 8 + 255) / 256, 256, 0, stream>>>(thr1, accv, fc_w, fc_b, out);
}

// Round 9
// 369.538 us; speedup vs baseline: 1.1714x; 1.1714x over previous
//
#include <hip/hip_runtime.h>
#include <hip/hip_bf16.h>
#include <stdint.h>

#define B_ 256
#define T_ 512
#define C_ 14
#define CO_ 32
#define H_ 128
#define G_ 512   // 4*H

__device__ __forceinline__ float sigm_fast(float x) {
  float e = __expf(-x);
  return __builtin_amdgcn_rcpf(1.f + e);
}
__device__ __forceinline__ float tanh_fast(float x) {
  float e = __expf(2.f * x);               // inf-safe: x>>0 -> 1, x<<0 -> -1
  return 1.f - 2.f * __builtin_amdgcn_rcpf(1.f + e);
}

// Fast path is provable: mem = o*tanh(syn) - reset*thr < 1 always (o<1,
// |tanh|<1). Spike needs mem - thr1 > 0, impossible when thr1 >= 1, so
// layer-1 spikes are identically zero for ANY x/weights.

// ---------------- Kernel 1: conv over time + Leaky spike (fallback) --------
__global__ __launch_bounds__(256) void k_conv_spike(
    const float* __restrict__ thr1_p, const float* __restrict__ x,
    const float* __restrict__ cw, const float* __restrict__ cb,
    unsigned int* __restrict__ cur1) {
  if (thr1_p[0] >= 1.0f) return;
  __shared__ float w_s[CO_ * C_ * 3];
  __shared__ float b_s[CO_];
  for (int i = threadIdx.x; i < CO_ * C_ * 3; i += blockDim.x) w_s[i] = cw[i];
  if (threadIdx.x < CO_) b_s[threadIdx.x] = cb[threadIdx.x];
  __syncthreads();
  int idx = blockIdx.x * blockDim.x + threadIdx.x;  // b*T + t
  if (idx >= B_ * T_) return;
  int b = idx / T_, t = idx % T_;
  float xin[3][C_];
#pragma unroll
  for (int k = 0; k < 3; ++k) {
    int tt = t + k - 1;
    if (tt < 0 || tt >= T_) {
#pragma unroll
      for (int c = 0; c < C_; ++c) xin[k][c] = 0.f;
    } else {
      const float* p = x + ((size_t)b * T_ + tt) * C_;
#pragma unroll
      for (int c = 0; c < C_; ++c) xin[k][c] = p[c];
    }
  }
  unsigned int bits = 0u;
  for (int oc = 0; oc < CO_; ++oc) {
    float s = b_s[oc];
    const float* wr = &w_s[oc * C_ * 3];
#pragma unroll
    for (int ic = 0; ic < C_; ++ic)
#pragma unroll
      for (int k = 0; k < 3; ++k) s = fmaf(xin[k][ic], wr[ic * 3 + k], s);
    if (s - 1.0f > 0.f) bits |= (1u << oc);
  }
  cur1[idx] = bits;
}

// ---------------- Kernel 2: honest SLSTM layer 1 (fallback only) -----------
__global__ __launch_bounds__(512, 2) void k_slstm1(
    const unsigned int* __restrict__ cur1,
    const float* __restrict__ w_ih, const float* __restrict__ w_hh,
    const float* __restrict__ b_ih, const float* __restrict__ b_hh,
    const float* __restrict__ thr_p, unsigned long long* __restrict__ spk_bits,
    unsigned int* __restrict__ count) {
  if (thr_p[0] >= 1.0f) return;  // spikes provably zero; count stays 0
  const int g = threadIdx.x;
  const int t0 = blockIdx.x * 2;
  const float thr = thr_p[0];
  float wih[32], whh[H_];
#pragma unroll
  for (int k = 0; k < 32; ++k) wih[k] = w_ih[g * 32 + k];
#pragma unroll
  for (int k = 0; k < H_; ++k) whh[k] = w_hh[g * H_ + k];
  const float bias = b_ih[g] + b_hh[g];
  __shared__ float mem_s[2][H_];
  __shared__ float gate_s[2][G_];
  float syn = 0.f;
  int cnt = 0;
  if (g < 256) mem_s[g >> 7][g & 127] = 0.f;
  __syncthreads();
  for (int b = 0; b < B_; ++b) {
    unsigned int bits0 = cur1[b * T_ + t0];
    unsigned int bits1 = cur1[b * T_ + t0 + 1];
    float s0 = bias, s1 = bias;
#pragma unroll
    for (int k = 0; k < 32; ++k) {
      s0 += ((bits0 >> k) & 1u) ? wih[k] : 0.f;
      s1 += ((bits1 >> k) & 1u) ? wih[k] : 0.f;
    }
#pragma unroll
    for (int k = 0; k < H_; ++k) {
      s0 = fmaf(whh[k], mem_s[0][k], s0);
      s1 = fmaf(whh[k], mem_s[1][k], s1);
    }
    gate_s[0][g] = s0;
    gate_s[1][g] = s1;
    __syncthreads();
    if (g < 256) {
      const int r = g >> 7, h = g & 127;
      float gi = gate_s[r][h];
      float gf = gate_s[r][h + 128];
      float gg = gate_s[r][h + 256];
      float go = gate_s[r][h + 384];
      float ii = 1.f / (1.f + expf(-gi));
      float ff = 1.f / (1.f + expf(-gf));
      float gt = tanhf(gg);
      float oo = 1.f / (1.f + expf(-go));
      float memp = mem_s[r][h];
      float rst = (memp - thr > 0.f) ? thr : 0.f;
      syn = ff * syn + ii * gt;
      float mm = oo * tanhf(syn) - rst;
      mem_s[r][h] = mm;
      bool spk = (mm - thr) > 0.f;
      cnt += spk ? 1 : 0;
      unsigned long long m = __ballot(spk);
      if ((g & 63) == 0)
        spk_bits[((size_t)b * T_ + t0 + r) * 2 + ((h >> 6) & 1)] = m;
    }
    __syncthreads();
  }
  if (g < 256) atomicAdd(&count[g & 127], (unsigned int)cnt);
}

// ---------------- Kernel 3: BN params from spike counts (both paths) -------
__global__ void k_bnprep(const unsigned int* __restrict__ count,
                         const float* __restrict__ gamma,
                         const float* __restrict__ beta,
                         float* __restrict__ a, float* __restrict__ c) {
  int h = threadIdx.x;
  if (h >= H_) return;
  const float inv_n = 1.f / (float)(B_ * T_);
  float mu = (float)count[h] * inv_n;
  float var = mu * (1.f - mu);
  float ai = gamma[h] / sqrtf(var + 1e-5f);
  a[h] = ai;
  c[h] = beta[h] - mu * ai;
}

// ---------------- Kernel 4: fold BN into layer-2 weights (cg both paths) ---
__global__ void k_fold(const float* __restrict__ thr1_p,
                       const float* __restrict__ w_ih2,
                       const float* __restrict__ b_ih2,
                       const float* __restrict__ b_hh2,
                       const float* __restrict__ a, const float* __restrict__ c,
                       float* __restrict__ W2p, float* __restrict__ cg) {
  int gi = blockIdx.x * blockDim.x + threadIdx.x;  // 0..511
  if (gi >= G_) return;
  const int fast = thr1_p[0] >= 1.0f;
  float s = b_ih2[gi] + b_hh2[gi];
  for (int h = 0; h < H_; ++h) {
    float w = w_ih2[gi * H_ + h];
    if (!fast) W2p[h * G_ + gi] = w * a[h];  // fallback-only matrix
    s = fmaf(w, c[h], s);
  }
  cg[gi] = s;
}

// ---------------- Kernel 5: honest SLSTM layer 2 (fallback only) -----------
__global__ __launch_bounds__(512, 2) void k_slstm2(
    const float* __restrict__ thr1_p,
    const unsigned long long* __restrict__ spk_bits,
    const float* __restrict__ w_hh, const float* __restrict__ W2p,
    const float* __restrict__ cg, const float* __restrict__ thr_p,
    float* __restrict__ acc_out) {
  if (thr1_p[0] >= 1.0f) return;  // fast path handled by k_traj
  const int g = threadIdx.x;
  const int t0 = blockIdx.x * 2;
  const float thr = thr_p[0];
  float whh[H_];
#pragma unroll
  for (int k = 0; k < H_; ++k) whh[k] = w_hh[g * H_ + k];
  const float bias = cg[g];
  __shared__ float mem_s[2][H_];
  __shared__ float gate_s[2][G_];
  float syn = 0.f, accv = 0.f;
  if (g < 256) mem_s[g >> 7][g & 127] = 0.f;
  __syncthreads();
  for (int b = 0; b < B_; ++b) {
    unsigned long long m00 = spk_bits[((size_t)b * T_ + t0) * 2 + 0];
    unsigned long long m01 = spk_bits[((size_t)b * T_ + t0) * 2 + 1];
    unsigned long long m10 = spk_bits[((size_t)b * T_ + t0 + 1) * 2 + 0];
    unsigned long long m11 = spk_bits[((size_t)b * T_ + t0 + 1) * 2 + 1];
    float s0 = bias, s1 = bias;
    while (m00) { int h = __ffsll(m00) - 1; m00 &= m00 - 1; s0 += W2p[h * G_ + g]; }
    while (m01) { int h = __ffsll(m01) - 1; m01 &= m01 - 1; s0 += W2p[(h + 64) * G_ + g]; }
    while (m10) { int h = __ffsll(m10) - 1; m10 &= m10 - 1; s1 += W2p[h * G_ + g]; }
    while (m11) { int h = __ffsll(m11) - 1; m11 &= m11 - 1; s1 += W2p[(h + 64) * G_ + g]; }
#pragma unroll
    for (int k = 0; k < H_; ++k) {
      s0 = fmaf(whh[k], mem_s[0][k], s0);
      s1 = fmaf(whh[k], mem_s[1][k], s1);
    }
    gate_s[0][g] = s0;
    gate_s[1][g] = s1;
    __syncthreads();
    if (g < 256) {
      const int r = g >> 7, h = g & 127;
      float gi = gate_s[r][h];
      float gf = gate_s[r][h + 128];
      float gg = gate_s[r][h + 256];
      float go = gate_s[r][h + 384];
      float ii = 1.f / (1.f + expf(-gi));
      float ff = 1.f / (1.f + expf(-gf));
      float gt = tanhf(gg);
      float oo = 1.f / (1.f + expf(-go));
      float memp = mem_s[r][h];
      float rst = (memp - thr > 0.f) ? thr : 0.f;
      syn = ff * syn + ii * gt;
      float mm = oo * tanhf(syn) - rst;
      mem_s[r][h] = mm;
      accv += mm;
    }
    __syncthreads();
  }
  if (g < 256) acc_out[(size_t)(t0 + (g >> 7)) * H_ + (g & 127)] = accv;
}

// ---------------- Kernel 5b: FAST layer 2 — single shared trajectory -------
// thr1>=1 -> layer-2 input = beta every row/step -> ONE 256-step trajectory.
// 512 threads, ONE gate per thread: 128 weight floats = 32 named float4
// (~190 regs incl. working set -> fits ARCH VGPRs v0-v255; waves_per_eu(2,2)
// pins the 256 budget; "v" pins now copy-free — round-8 lesson: 256 wt/thread
// forced AGPRs + per-step accvgpr copy storms).
// Phase 2 is REPLICATED per wave: lane l redundantly updates h=l and h=l+64
// from the shared preact buffer, so new mem lands in each wave's own vm0/vm1
// VGPRs -> no mem LDS round-trip, ONE barrier/step (gbuf double-buffered).
#define PIN4(v) asm volatile("" : "+v"(v.x), "+v"(v.y), "+v"(v.z), "+v"(v.w))
#define PIN16(P) PIN4(P##0); PIN4(P##1); PIN4(P##2); PIN4(P##3);

#define LD16(P, p, o)                              \
  float4 P##0 = *(const float4*)((p) + (o));       \
  float4 P##1 = *(const float4*)((p) + (o) + 4);   \
  float4 P##2 = *(const float4*)((p) + (o) + 8);   \
  float4 P##3 = *(const float4*)((p) + (o) + 12);

#define RLF(v, k) __uint_as_float(__builtin_amdgcn_readlane((v), (k)))

// NOTE: (P##0).x — parens required; "P##0.x" lexes "0.x" as one pp-number.
#define DOT16(P, vmx, base) {                          \
    float mk;                                          \
    mk = RLF(vmx, (base) + 0);  a0 = fmaf((P##0).x, mk, a0); \
    mk = RLF(vmx, (base) + 1);  a1 = fmaf((P##0).y, mk, a1); \
    mk = RLF(vmx, (base) + 2);  a2 = fmaf((P##0).z, mk, a2); \
    mk = RLF(vmx, (base) + 3);  a3 = fmaf((P##0).w, mk, a3); \
    mk = RLF(vmx, (base) + 4);  a0 = fmaf((P##1).x, mk, a0); \
    mk = RLF(vmx, (base) + 5);  a1 = fmaf((P##1).y, mk, a1); \
    mk = RLF(vmx, (base) + 6);  a2 = fmaf((P##1).z, mk, a2); \
    mk = RLF(vmx, (base) + 7);  a3 = fmaf((P##1).w, mk, a3); \
    mk = RLF(vmx, (base) + 8);  a0 = fmaf((P##2).x, mk, a0); \
    mk = RLF(vmx, (base) + 9);  a1 = fmaf((P##2).y, mk, a1); \
    mk = RLF(vmx, (base) + 10); a2 = fmaf((P##2).z, mk, a2); \
    mk = RLF(vmx, (base) + 11); a3 = fmaf((P##2).w, mk, a3); \
    mk = RLF(vmx, (base) + 12); a0 = fmaf((P##3).x, mk, a0); \
    mk = RLF(vmx, (base) + 13); a1 = fmaf((P##3).y, mk, a1); \
    mk = RLF(vmx, (base) + 14); a2 = fmaf((P##3).z, mk, a2); \
    mk = RLF(vmx, (base) + 15); a3 = fmaf((P##3).w, mk, a3); \
  }

__global__ __launch_bounds__(512)
__attribute__((amdgpu_waves_per_eu(2, 2))) void k_traj(
    const float* __restrict__ thr1_p, const float* __restrict__ w_hh,
    const float* __restrict__ cg, const float* __restrict__ thr_p,
    const float* __restrict__ fc_w, const float* __restrict__ fc_b,
    float* __restrict__ out) {
  if (thr1_p[0] < 1.0f) return;
  const int g = threadIdx.x;   // gate 0..511
  const int lane = g & 63;
  const float thr = thr_p[0];

  const float* wr = w_hh + (size_t)g * H_;
  LD16(Pa, wr, 0)  LD16(Pb, wr, 16) LD16(Pc, wr, 32) LD16(Pd, wr, 48)
  LD16(Pe, wr, 64) LD16(Pf, wr, 80) LD16(Pg, wr, 96) LD16(Ph, wr, 112)
  float bias = cg[g];

  __shared__ float gbuf[2][G_];   // double-buffered preacts
  __shared__ float red_s[H_ + 8];
  // replicated per-wave state for h0 = lane, h1 = lane + 64
  float syn0 = 0.f, syn1 = 0.f, memp0 = 0.f, memp1 = 0.f;
  float accm0 = 0.f, accm1 = 0.f;
  int vm0 = 0, vm1 = 0;  // bits of mem[lane], mem[64+lane]; mem_0 = 0

  for (int b = 0; b < B_; ++b) {
    PIN16(Pa) PIN16(Pb) PIN16(Pc) PIN16(Pd)
    PIN16(Pe) PIN16(Pf) PIN16(Pg) PIN16(Ph)
    asm volatile("" : "+v"(bias));
    // phase 1: full 128-dot for gate g; mem operands via readlane (SGPR)
    float a0 = bias, a1 = 0.f, a2 = 0.f, a3 = 0.f;
    DOT16(Pa, vm0, 0)  DOT16(Pb, vm0, 16) DOT16(Pc, vm0, 32) DOT16(Pd, vm0, 48)
    DOT16(Pe, vm1, 0)  DOT16(Pf, vm1, 16) DOT16(Pg, vm1, 32) DOT16(Ph, vm1, 48)
    float* wb = gbuf[b & 1];
    wb[g] = (a0 + a1) + (a2 + a3);
    __syncthreads();
    // phase 2 (replicated in every wave): update h0 = lane, h1 = lane+64
    {
      float i0 = sigm_fast(wb[lane]);
      float f0 = sigm_fast(wb[lane + 128]);
      float G0 = tanh_fast(wb[lane + 256]);
      float o0 = sigm_fast(wb[lane + 384]);
      float i1 = sigm_fast(wb[lane + 64]);
      float f1 = sigm_fast(wb[lane + 192]);
      float G1 = tanh_fast(wb[lane + 320]);
      float o1 = sigm_fast(wb[lane + 448]);
      float rst0 = (memp0 - thr > 0.f) ? thr : 0.f;  // honest (thr2 runtime)
      float rst1 = (memp1 - thr > 0.f) ? thr : 0.f;
      syn0 = f0 * syn0 + i0 * G0;
      syn1 = f1 * syn1 + i1 * G1;
      float mm0 = o0 * tanh_fast(syn0) - rst0;
      float mm1 = o1 * tanh_fast(syn1) - rst1;
      memp0 = mm0; memp1 = mm1;
      accm0 += mm0; accm1 += mm1;
      vm0 = __float_as_int(mm0);
      vm1 = __float_as_int(mm1);
    }
    // no 2nd barrier: next iter writes gbuf[(b+1)&1] != the buffer just read
  }
  // mean over steps -> FC (8 outputs) -> broadcast to all 512 rows
  if (g < 64) {
    red_s[lane] = accm0 * (1.f / 256.f);
    red_s[lane + 64] = accm1 * (1.f / 256.f);
  }
  __syncthreads();
  if (g < 8) {
    float s = fc_b[g];
    const float* fw = fc_w + g * H_;
    for (int k = 0; k < H_; ++k) s = fmaf(red_s[k], fw[k], s);
    red_s[H_ + g] = s;
  }
  __syncthreads();
  for (int idx = g; idx < T_ * 8; idx += 512) out[idx] = red_s[H_ + (idx & 7)];
}

// ---------------- Kernel 6: final mean + FC (fallback only) ----------------
__global__ void k_out(const float* __restrict__ thr1_p,
                      const float* __restrict__ accv,
                      const float* __restrict__ fc_w,
                      const float* __restrict__ fc_b, float* __restrict__ out) {
  if (thr1_p[0] >= 1.0f) return;
  int idx = blockIdx.x * blockDim.x + threadIdx.x;  // t*8+n
  if (idx >= T_ * 8) return;
  int t = idx >> 3, n = idx & 7;
  float s = fc_b[n];
  for (int h = 0; h < H_; ++h)
    s = fmaf(accv[t * H_ + h] * (1.f / 256.f), fc_w[n * H_ + h], s);
  out[idx] = s;
}

extern "C" void kernel_launch(void* const* d_in, const int* in_sizes, int n_in,
                              void* d_out, int out_size, void* d_ws, size_t ws_size,
                              hipStream_t stream) {
  const float* x       = (const float*)d_in[0];
  const float* conv_w  = (const float*)d_in[1];
  const float* conv_b  = (const float*)d_in[2];
  const float* w_ih1   = (const float*)d_in[3];
  const float* w_hh1   = (const float*)d_in[4];
  const float* b_ih1   = (const float*)d_in[5];
  const float* b_hh1   = (const float*)d_in[6];
  const float* thr1    = (const float*)d_in[7];
  const float* w_ih2   = (const float*)d_in[8];
  const float* w_hh2   = (const float*)d_in[9];
  const float* b_ih2   = (const float*)d_in[10];
  const float* b_hh2   = (const float*)d_in[11];
  const float* thr2    = (const float*)d_in[12];
  const float* bn_g    = (const float*)d_in[13];
  const float* bn_b    = (const float*)d_in[14];
  const float* fc_w    = (const float*)d_in[15];
  const float* fc_b    = (const float*)d_in[16];
  float* out = (float*)d_out;

  char* ws = (char*)d_ws;
  unsigned int* cur1       = (unsigned int*)(ws);                    // 512 KB
  unsigned long long* spk  = (unsigned long long*)(ws + (512 << 10));// 2 MB
  unsigned int* count      = (unsigned int*)(ws + (2560 << 10));     // 512 B
  float* a                 = (float*)(ws + (2561 << 10));            // 512 B
  float* c                 = (float*)(ws + (2562 << 10));            // 512 B
  float* cg                = (float*)(ws + (2563 << 10));            // 2 KB
  float* W2p               = (float*)(ws + (2566 << 10));            // 256 KB
  float* accv              = (float*)(ws + (2822 << 10));            // 256 KB

  hipMemsetAsync(count, 0, H_ * sizeof(unsigned int), stream);
  k_conv_spike<<<(B_ * T_ + 255) / 256, 256, 0, stream>>>(thr1, x, conv_w,
                                                          conv_b, cur1);
  k_slstm1<<<T_ / 2, 512, 0, stream>>>(cur1, w_ih1, w_hh1, b_ih1, b_hh1, thr1,
                                       spk, count);
  k_bnprep<<<1, 128, 0, stream>>>(count, bn_g, bn_b, a, c);
  k_fold<<<1, 512, 0, stream>>>(thr1, w_ih2, b_ih2, b_hh2, a, c, W2p, cg);
  k_slstm2<<<T_ / 2, 512, 0, stream>>>(thr1, spk, w_hh2, W2p, cg, thr2, accv);
  k_traj<<<1, 512, 0, stream>>>(thr1, w_hh2, cg, thr2, fc_w, fc_b, out);
  k_out<<<(T_ * 8 + 255) / 256, 256, 0, stream>>>(thr1, accv, fc_w, fc_b, out);
}

// Round 11
// 317.730 us; speedup vs baseline: 1.3624x; 1.1631x over previous
//
#include <hip/hip_runtime.h>
#include <hip/hip_bf16.h>
#include <stdint.h>

#define B_ 256
#define T_ 512
#define C_ 14
#define CO_ 32
#define H_ 128
#define G_ 512   // 4*H

__device__ __forceinline__ float sigm_fast(float x) {
  float e = __expf(-x);
  return __builtin_amdgcn_rcpf(1.f + e);
}
__device__ __forceinline__ float tanh_fast(float x) {
  float e = __expf(2.f * x);               // inf-safe: x>>0 -> 1, x<<0 -> -1
  return 1.f - 2.f * __builtin_amdgcn_rcpf(1.f + e);
}

// Fast path is provable: mem = o*tanh(syn) - reset*thr < 1 always (o<1,
// |tanh|<1). Spike needs mem - thr1 > 0, impossible when thr1 >= 1, so
// layer-1 spikes are identically zero for ANY x/weights.

// ---------------- Kernel 1: conv over time + Leaky spike (fallback) --------
__global__ __launch_bounds__(256) void k_conv_spike(
    const float* __restrict__ thr1_p, const float* __restrict__ x,
    const float* __restrict__ cw, const float* __restrict__ cb,
    unsigned int* __restrict__ cur1) {
  if (thr1_p[0] >= 1.0f) return;
  __shared__ float w_s[CO_ * C_ * 3];
  __shared__ float b_s[CO_];
  for (int i = threadIdx.x; i < CO_ * C_ * 3; i += blockDim.x) w_s[i] = cw[i];
  if (threadIdx.x < CO_) b_s[threadIdx.x] = cb[threadIdx.x];
  __syncthreads();
  int idx = blockIdx.x * blockDim.x + threadIdx.x;  // b*T + t
  if (idx >= B_ * T_) return;
  int b = idx / T_, t = idx % T_;
  float xin[3][C_];
#pragma unroll
  for (int k = 0; k < 3; ++k) {
    int tt = t + k - 1;
    if (tt < 0 || tt >= T_) {
#pragma unroll
      for (int c = 0; c < C_; ++c) xin[k][c] = 0.f;
    } else {
      const float* p = x + ((size_t)b * T_ + tt) * C_;
#pragma unroll
      for (int c = 0; c < C_; ++c) xin[k][c] = p[c];
    }
  }
  unsigned int bits = 0u;
  for (int oc = 0; oc < CO_; ++oc) {
    float s = b_s[oc];
    const float* wr = &w_s[oc * C_ * 3];
#pragma unroll
    for (int ic = 0; ic < C_; ++ic)
#pragma unroll
      for (int k = 0; k < 3; ++k) s = fmaf(xin[k][ic], wr[ic * 3 + k], s);
    if (s - 1.0f > 0.f) bits |= (1u << oc);
  }
  cur1[idx] = bits;
}

// ---------------- Kernel 2: honest SLSTM layer 1 (fallback only) -----------
__global__ __launch_bounds__(512, 2) void k_slstm1(
    const unsigned int* __restrict__ cur1,
    const float* __restrict__ w_ih, const float* __restrict__ w_hh,
    const float* __restrict__ b_ih, const float* __restrict__ b_hh,
    const float* __restrict__ thr_p, unsigned long long* __restrict__ spk_bits,
    unsigned int* __restrict__ count) {
  if (thr_p[0] >= 1.0f) return;  // spikes provably zero; count stays 0
  const int g = threadIdx.x;
  const int t0 = blockIdx.x * 2;
  const float thr = thr_p[0];
  float wih[32], whh[H_];
#pragma unroll
  for (int k = 0; k < 32; ++k) wih[k] = w_ih[g * 32 + k];
#pragma unroll
  for (int k = 0; k < H_; ++k) whh[k] = w_hh[g * H_ + k];
  const float bias = b_ih[g] + b_hh[g];
  __shared__ float mem_s[2][H_];
  __shared__ float gate_s[2][G_];
  float syn = 0.f;
  int cnt = 0;
  if (g < 256) mem_s[g >> 7][g & 127] = 0.f;
  __syncthreads();
  for (int b = 0; b < B_; ++b) {
    unsigned int bits0 = cur1[b * T_ + t0];
    unsigned int bits1 = cur1[b * T_ + t0 + 1];
    float s0 = bias, s1 = bias;
#pragma unroll
    for (int k = 0; k < 32; ++k) {
      s0 += ((bits0 >> k) & 1u) ? wih[k] : 0.f;
      s1 += ((bits1 >> k) & 1u) ? wih[k] : 0.f;
    }
#pragma unroll
    for (int k = 0; k < H_; ++k) {
      s0 = fmaf(whh[k], mem_s[0][k], s0);
      s1 = fmaf(whh[k], mem_s[1][k], s1);
    }
    gate_s[0][g] = s0;
    gate_s[1][g] = s1;
    __syncthreads();
    if (g < 256) {
      const int r = g >> 7, h = g & 127;
      float gi = gate_s[r][h];
      float gf = gate_s[r][h + 128];
      float gg = gate_s[r][h + 256];
      float go = gate_s[r][h + 384];
      float ii = 1.f / (1.f + expf(-gi));
      float ff = 1.f / (1.f + expf(-gf));
      float gt = tanhf(gg);
      float oo = 1.f / (1.f + expf(-go));
      float memp = mem_s[r][h];
      float rst = (memp - thr > 0.f) ? thr : 0.f;
      syn = ff * syn + ii * gt;
      float mm = oo * tanhf(syn) - rst;
      mem_s[r][h] = mm;
      bool spk = (mm - thr) > 0.f;
      cnt += spk ? 1 : 0;
      unsigned long long m = __ballot(spk);
      if ((g & 63) == 0)
        spk_bits[((size_t)b * T_ + t0 + r) * 2 + ((h >> 6) & 1)] = m;
    }
    __syncthreads();
  }
  if (g < 256) atomicAdd(&count[g & 127], (unsigned int)cnt);
}

// ---------------- Kernel 3: BN params from spike counts (both paths) -------
__global__ void k_bnprep(const unsigned int* __restrict__ count,
                         const float* __restrict__ gamma,
                         const float* __restrict__ beta,
                         float* __restrict__ a, float* __restrict__ c) {
  int h = threadIdx.x;
  if (h >= H_) return;
  const float inv_n = 1.f / (float)(B_ * T_);
  float mu = (float)count[h] * inv_n;
  float var = mu * (1.f - mu);
  float ai = gamma[h] / sqrtf(var + 1e-5f);
  a[h] = ai;
  c[h] = beta[h] - mu * ai;
}

// ---------------- Kernel 4: fold BN into layer-2 weights (cg both paths) ---
__global__ void k_fold(const float* __restrict__ thr1_p,
                       const float* __restrict__ w_ih2,
                       const float* __restrict__ b_ih2,
                       const float* __restrict__ b_hh2,
                       const float* __restrict__ a, const float* __restrict__ c,
                       float* __restrict__ W2p, float* __restrict__ cg) {
  int gi = blockIdx.x * blockDim.x + threadIdx.x;  // 0..511
  if (gi >= G_) return;
  const int fast = thr1_p[0] >= 1.0f;
  float s = b_ih2[gi] + b_hh2[gi];
  for (int h = 0; h < H_; ++h) {
    float w = w_ih2[gi * H_ + h];
    if (!fast) W2p[h * G_ + gi] = w * a[h];  // fallback-only matrix
    s = fmaf(w, c[h], s);
  }
  cg[gi] = s;
}

// ---------------- Kernel 5: honest SLSTM layer 2 (fallback only) -----------
__global__ __launch_bounds__(512, 2) void k_slstm2(
    const float* __restrict__ thr1_p,
    const unsigned long long* __restrict__ spk_bits,
    const float* __restrict__ w_hh, const float* __restrict__ W2p,
    const float* __restrict__ cg, const float* __restrict__ thr_p,
    float* __restrict__ acc_out) {
  if (thr1_p[0] >= 1.0f) return;  // fast path handled by k_traj
  const int g = threadIdx.x;
  const int t0 = blockIdx.x * 2;
  const float thr = thr_p[0];
  float whh[H_];
#pragma unroll
  for (int k = 0; k < H_; ++k) whh[k] = w_hh[g * H_ + k];
  const float bias = cg[g];
  __shared__ float mem_s[2][H_];
  __shared__ float gate_s[2][G_];
  float syn = 0.f, accv = 0.f;
  if (g < 256) mem_s[g >> 7][g & 127] = 0.f;
  __syncthreads();
  for (int b = 0; b < B_; ++b) {
    unsigned long long m00 = spk_bits[((size_t)b * T_ + t0) * 2 + 0];
    unsigned long long m01 = spk_bits[((size_t)b * T_ + t0) * 2 + 1];
    unsigned long long m10 = spk_bits[((size_t)b * T_ + t0 + 1) * 2 + 0];
    unsigned long long m11 = spk_bits[((size_t)b * T_ + t0 + 1) * 2 + 1];
    float s0 = bias, s1 = bias;
    while (m00) { int h = __ffsll(m00) - 1; m00 &= m00 - 1; s0 += W2p[h * G_ + g]; }
    while (m01) { int h = __ffsll(m01) - 1; m01 &= m01 - 1; s0 += W2p[(h + 64) * G_ + g]; }
    while (m10) { int h = __ffsll(m10) - 1; m10 &= m10 - 1; s1 += W2p[h * G_ + g]; }
    while (m11) { int h = __ffsll(m11) - 1; m11 &= m11 - 1; s1 += W2p[(h + 64) * G_ + g]; }
#pragma unroll
    for (int k = 0; k < H_; ++k) {
      s0 = fmaf(whh[k], mem_s[0][k], s0);
      s1 = fmaf(whh[k], mem_s[1][k], s1);
    }
    gate_s[0][g] = s0;
    gate_s[1][g] = s1;
    __syncthreads();
    if (g < 256) {
      const int r = g >> 7, h = g & 127;
      float gi = gate_s[r][h];
      float gf = gate_s[r][h + 128];
      float gg = gate_s[r][h + 256];
      float go = gate_s[r][h + 384];
      float ii = 1.f / (1.f + expf(-gi));
      float ff = 1.f / (1.f + expf(-gf));
      float gt = tanhf(gg);
      float oo = 1.f / (1.f + expf(-go));
      float memp = mem_s[r][h];
      float rst = (memp - thr > 0.f) ? thr : 0.f;
      syn = ff * syn + ii * gt;
      float mm = oo * tanhf(syn) - rst;
      mem_s[r][h] = mm;
      accv += mm;
    }
    __syncthreads();
  }
  if (g < 256) acc_out[(size_t)(t0 + (g >> 7)) * H_ + (g & 127)] = accv;
}

// ---------------- Kernel 5b: FAST layer 2 — single shared trajectory -------
// thr1>=1 -> layer-2 input = beta every row/step -> ONE 256-step trajectory.
// 512 threads, ONE gate per thread, waves_per_eu(2,2) (256-reg budget; live
// set ~190 fits arch VGPRs). Round-9/10 lessons combined:
//  - per-iteration "v" pins on AGPR-parked values force copy storms (r9);
//  - raw flat-asm loads fault (r10);
//  - remat-blocking only needs the pin ONCE, outside the loop: an
//    asm-defined value cannot be rematerialized, so it must stay
//    register-resident across the loop at zero per-iteration cost.
#define PIN4(v) asm volatile("" : "+v"(v.x), "+v"(v.y), "+v"(v.z), "+v"(v.w))
#define PIN16(P) PIN4(P##0); PIN4(P##1); PIN4(P##2); PIN4(P##3);

#define LD16(P, p, o)                              \
  float4 P##0 = *(const float4*)((p) + (o));       \
  float4 P##1 = *(const float4*)((p) + (o) + 4);   \
  float4 P##2 = *(const float4*)((p) + (o) + 8);   \
  float4 P##3 = *(const float4*)((p) + (o) + 12);

#define RLF(v, k) __uint_as_float(__builtin_amdgcn_readlane((v), (k)))

// NOTE: (P##0).x — parens required; "P##0.x" lexes "0.x" as one pp-number.
#define DOT16(P, vmx, base) {                          \
    float mk;                                          \
    mk = RLF(vmx, (base) + 0);  a0 = fmaf((P##0).x, mk, a0); \
    mk = RLF(vmx, (base) + 1);  a1 = fmaf((P##0).y, mk, a1); \
    mk = RLF(vmx, (base) + 2);  a2 = fmaf((P##0).z, mk, a2); \
    mk = RLF(vmx, (base) + 3);  a3 = fmaf((P##0).w, mk, a3); \
    mk = RLF(vmx, (base) + 4);  a0 = fmaf((P##1).x, mk, a0); \
    mk = RLF(vmx, (base) + 5);  a1 = fmaf((P##1).y, mk, a1); \
    mk = RLF(vmx, (base) + 6);  a2 = fmaf((P##1).z, mk, a2); \
    mk = RLF(vmx, (base) + 7);  a3 = fmaf((P##1).w, mk, a3); \
    mk = RLF(vmx, (base) + 8);  a0 = fmaf((P##2).x, mk, a0); \
    mk = RLF(vmx, (base) + 9);  a1 = fmaf((P##2).y, mk, a1); \
    mk = RLF(vmx, (base) + 10); a2 = fmaf((P##2).z, mk, a2); \
    mk = RLF(vmx, (base) + 11); a3 = fmaf((P##2).w, mk, a3); \
    mk = RLF(vmx, (base) + 12); a0 = fmaf((P##3).x, mk, a0); \
    mk = RLF(vmx, (base) + 13); a1 = fmaf((P##3).y, mk, a1); \
    mk = RLF(vmx, (base) + 14); a2 = fmaf((P##3).z, mk, a2); \
    mk = RLF(vmx, (base) + 15); a3 = fmaf((P##3).w, mk, a3); \
  }

__global__ __launch_bounds__(512)
__attribute__((amdgpu_waves_per_eu(2, 2))) void k_traj(
    const float* __restrict__ thr1_p, const float* __restrict__ w_hh,
    const float* __restrict__ cg, const float* __restrict__ thr_p,
    const float* __restrict__ fc_w, const float* __restrict__ fc_b,
    float* __restrict__ out) {
  if (thr1_p[0] < 1.0f) return;
  const int g = threadIdx.x;   // gate 0..511
  const int lane = g & 63;
  const float thr = thr_p[0];

  const float* wr = w_hh + (size_t)g * H_;
  LD16(Pa, wr, 0)  LD16(Pb, wr, 16) LD16(Pc, wr, 32) LD16(Pd, wr, 48)
  LD16(Pe, wr, 64) LD16(Pf, wr, 80) LD16(Pg, wr, 96) LD16(Ph, wr, 112)
  float bias = cg[g];
  // ONE-TIME pins (outside the loop): weights become asm-defined values ->
  // non-rematerializable, must stay register-resident; no per-step cost.
  PIN16(Pa) PIN16(Pb) PIN16(Pc) PIN16(Pd)
  PIN16(Pe) PIN16(Pf) PIN16(Pg) PIN16(Ph)
  asm volatile("" : "+v"(bias));

  __shared__ float gbuf[2][G_];   // double-buffered preacts
  __shared__ float red_s[H_ + 8];
  // replicated per-wave state for h0 = lane, h1 = lane + 64
  float syn0 = 0.f, syn1 = 0.f, memp0 = 0.f, memp1 = 0.f;
  float accm0 = 0.f, accm1 = 0.f;
  int vm0 = 0, vm1 = 0;  // bits of mem[lane], mem[64+lane]; mem_0 = 0

  for (int b = 0; b < B_; ++b) {
    // phase 1: full 128-dot for gate g; mem operands via readlane (SGPR)
    float a0 = bias, a1 = 0.f, a2 = 0.f, a3 = 0.f;
    DOT16(Pa, vm0, 0)  DOT16(Pb, vm0, 16) DOT16(Pc, vm0, 32) DOT16(Pd, vm0, 48)
    DOT16(Pe, vm1, 0)  DOT16(Pf, vm1, 16) DOT16(Pg, vm1, 32) DOT16(Ph, vm1, 48)
    float* wb = gbuf[b & 1];
    wb[g] = (a0 + a1) + (a2 + a3);
    __syncthreads();
    // phase 2 (replicated in every wave): update h0 = lane, h1 = lane+64
    {
      float i0 = sigm_fast(wb[lane]);
      float f0 = sigm_fast(wb[lane + 128]);
      float G0 = tanh_fast(wb[lane + 256]);
      float o0 = sigm_fast(wb[lane + 384]);
      float i1 = sigm_fast(wb[lane + 64]);
      float f1 = sigm_fast(wb[lane + 192]);
      float G1 = tanh_fast(wb[lane + 320]);
      float o1 = sigm_fast(wb[lane + 448]);
      float rst0 = (memp0 - thr > 0.f) ? thr : 0.f;  // honest (thr2 runtime)
      float rst1 = (memp1 - thr > 0.f) ? thr : 0.f;
      syn0 = f0 * syn0 + i0 * G0;
      syn1 = f1 * syn1 + i1 * G1;
      float mm0 = o0 * tanh_fast(syn0) - rst0;
      float mm1 = o1 * tanh_fast(syn1) - rst1;
      memp0 = mm0; memp1 = mm1;
      accm0 += mm0; accm1 += mm1;
      vm0 = __float_as_int(mm0);
      vm1 = __float_as_int(mm1);
    }
    // no 2nd barrier: next iter writes gbuf[(b+1)&1] != the buffer just read
  }
  // mean over steps -> FC (8 outputs) -> broadcast to all 512 rows
  if (g < 64) {
    red_s[lane] = accm0 * (1.f / 256.f);
    red_s[lane + 64] = accm1 * (1.f / 256.f);
  }
  __syncthreads();
  if (g < 8) {
    float s = fc_b[g];
    const float* fw = fc_w + g * H_;
    for (int k = 0; k < H_; ++k) s = fmaf(red_s[k], fw[k], s);
    red_s[H_ + g] = s;
  }
  __syncthreads();
  for (int idx = g; idx < T_ * 8; idx += 512) out[idx] = red_s[H_ + (idx & 7)];
}

// ---------------- Kernel 6: final mean + FC (fallback only) ----------------
__global__ void k_out(const float* __restrict__ thr1_p,
                      const float* __restrict__ accv,
                      const float* __restrict__ fc_w,
                      const float* __restrict__ fc_b, float* __restrict__ out) {
  if (thr1_p[0] >= 1.0f) return;
  int idx = blockIdx.x * blockDim.x + threadIdx.x;  // t*8+n
  if (idx >= T_ * 8) return;
  int t = idx >> 3, n = idx & 7;
  float s = fc_b[n];
  for (int h = 0; h < H_; ++h)
    s = fmaf(accv[t * H_ + h] * (1.f / 256.f), fc_w[n * H_ + h], s);
  out[idx] = s;
}

extern "C" void kernel_launch(void* const* d_in, const int* in_sizes, int n_in,
                              void* d_out, int out_size, void* d_ws, size_t ws_size,
                              hipStream_t stream) {
  const float* x       = (const float*)d_in[0];
  const float* conv_w  = (const float*)d_in[1];
  const float* conv_b  = (const float*)d_in[2];
  const float* w_ih1   = (const float*)d_in[3];
  const float* w_hh1   = (const float*)d_in[4];
  const float* b_ih1   = (const float*)d_in[5];
  const float* b_hh1   = (const float*)d_in[6];
  const float* thr1    = (const float*)d_in[7];
  const float* w_ih2   = (const float*)d_in[8];
  const float* w_hh2   = (const float*)d_in[9];
  const float* b_ih2   = (const float*)d_in[10];
  const float* b_hh2   = (const float*)d_in[11];
  const float* thr2    = (const float*)d_in[12];
  const float* bn_g    = (const float*)d_in[13];
  const float* bn_b    = (const float*)d_in[14];
  const float* fc_w    = (const float*)d_in[15];
  const float* fc_b    = (const float*)d_in[16];
  float* out = (float*)d_out;

  char* ws = (char*)d_ws;
  unsigned int* cur1       = (unsigned int*)(ws);                    // 512 KB
  unsigned long long* spk  = (unsigned long long*)(ws + (512 << 10));// 2 MB
  unsigned int* count      = (unsigned int*)(ws + (2560 << 10));     // 512 B
  float* a                 = (float*)(ws + (2561 << 10));            // 512 B
  float* c                 = (float*)(ws + (2562 << 10));            // 512 B
  float* cg                = (float*)(ws + (2563 << 10));            // 2 KB
  float* W2p               = (float*)(ws + (2566 << 10));            // 256 KB
  float* accv              = (float*)(ws + (2822 << 10));            // 256 KB

  hipMemsetAsync(count, 0, H_ * sizeof(unsigned int), stream);
  k_conv_spike<<<(B_ * T_ + 255) / 256, 256, 0, stream>>>(thr1, x, conv_w,
                                                          conv_b, cur1);
  k_slstm1<<<T_ / 2, 512, 0, stream>>>(cur1, w_ih1, w_hh1, b_ih1, b_hh1, thr1,
                                       spk, count);
  k_bnprep<<<1, 128, 0, stream>>>(count, bn_g, bn_b, a, c);
  k_fold<<<1, 512, 0, stream>>>(thr1, w_ih2, b_ih2, b_hh2, a, c, W2p, cg);
  k_slstm2<<<T_ / 2, 512, 0, stream>>>(thr1, spk, w_hh2, W2p, cg, thr2, accv);
  k_traj<<<1, 512, 0, stream>>>(thr1, w_hh2, cg, thr2, fc_w, fc_b, out);
  k_out<<<(T_ * 8 + 255) / 256, 256, 0, stream>>>(thr1, accv, fc_w, fc_b, out);
}